// Round 15
// baseline (2411.977 us; speedup 1.0000x reference)
//
#include <hip/hip_runtime.h>
#include <hip/hip_bf16.h>

typedef unsigned long long ull;

#define BN 4
#define CH 128
#define NP 4096
#define KNB 10
#define EPSI 1e-5f
#define GM_PTS 16
#define CA_PTS 8

__device__ __forceinline__ ull shfl_xor_u64(ull v, int mask) {
    unsigned lo = (unsigned)(v & 0xFFFFFFFFu);
    unsigned hi = (unsigned)(v >> 32);
    lo = __shfl_xor(lo, mask);
    hi = __shfl_xor(hi, mask);
    return ((ull)hi << 32) | lo;
}

__device__ __forceinline__ int clampj(int j) { return ((unsigned)j < (unsigned)NP) ? j : 0; }

// ---------------- weight packing ----------------
__global__ void pack_convA(const float* __restrict__ w, float* __restrict__ WT) {
    int i = blockIdx.x * 256 + threadIdx.x;
    if (i >= 4 * CH * CH) return;
    int co = i % CH, ci = (i / CH) % CH, s = i / (CH * CH);
    float val;
    if (s == 0) {
        val = 0.f;
        for (int dk = 0; dk < 3; dk++)
            val += w[(co * 256 + ci) * 3 + dk] - w[(co * 256 + 128 + ci) * 3 + dk];
    } else {
        val = w[(co * 256 + 128 + ci) * 3 + (s - 1)];
    }
    WT[i] = val;
}

__global__ void pack_convB(const float* __restrict__ w, float* __restrict__ WT) {
    int i = blockIdx.x * 256 + threadIdx.x;
    if (i >= 3 * CH * CH) return;
    int co = i % CH, ci = (i / CH) % CH, dk = i / (CH * CH);
    WT[i] = w[(co * CH + ci) * 3 + dk];
}

__global__ void pack_uv(const float* __restrict__ w, float* __restrict__ WuT,
                        float* __restrict__ WnT, int Cout) {
    int i = blockIdx.x * 256 + threadIdx.x;
    if (i >= Cout * CH) return;
    int co = i % Cout, ci = i / Cout;
    float a = w[co * 256 + ci], b = w[co * 256 + 128 + ci];
    WuT[i] = a - b;
    WnT[i] = b;
}

__global__ void pack_plain(const float* __restrict__ w, float* __restrict__ WT, int Cin, int Cout) {
    int i = blockIdx.x * 256 + threadIdx.x;
    if (i >= Cin * Cout) return;
    int co = i % Cout, ci = i / Cout;
    WT[i] = w[co * Cin + ci];
}

// ---------------- features transpose ----------------
__global__ void ftrans_kernel(const float* __restrict__ feats, float* __restrict__ F) {
    int i = blockIdx.x * 256 + threadIdx.x;
    if (i >= BN * CH * NP) return;
    int n = i % NP, c = (i / NP) % CH, b = i / (NP * CH);
    F[(b * NP + n) * CH + c] = feats[i];
}

// ---------------- KNN ----------------
__global__ void knn_kernel(const float* __restrict__ coords, int* __restrict__ IDX) {
    int gw = blockIdx.x * 4 + (threadIdx.x >> 6);
    int b = gw / NP;
    int n = gw % NP;
    int lane = threadIdx.x & 63;
    float xn = coords[(b * 2 + 0) * NP + n];
    float yn = coords[(b * 2 + 1) * NP + n];
    float sn = __fadd_rn(__fmul_rn(xn, xn), __fmul_rn(yn, yn));
    ull a[11];
    #pragma unroll
    for (int q = 0; q < 11; q++) a[q] = 0xFFFFFFFFFFFFFFFFULL;
    for (int m = lane; m < NP; m += 64) {
        float xm = coords[(b * 2 + 0) * NP + m];
        float ym = coords[(b * 2 + 1) * NP + m];
        float sm = __fadd_rn(__fmul_rn(xm, xm), __fmul_rn(ym, ym));
        float dot = __fmaf_rn(yn, ym, __fmul_rn(xn, xm));
        float d = __fsub_rn(__fadd_rn(sn, sm), __fmul_rn(2.0f, dot));
        d = fmaxf(d, 1e-12f);
        ull key = ((ull)__float_as_uint(d) << 32) | (unsigned)m;
        if (key < a[10]) {
            a[10] = key;
            #pragma unroll
            for (int q = 10; q > 0; --q)
                if (a[q] < a[q - 1]) { ull t = a[q]; a[q] = a[q - 1]; a[q - 1] = t; }
        }
    }
    int p = 0;
    for (int r = 0; r < 11; ++r) {
        ull k = (p < 11) ? a[p] : 0xFFFFFFFFFFFFFFFFULL;
        ull mk = k;
        #pragma unroll
        for (int off = 1; off < 64; off <<= 1) {
            ull o = shfl_xor_u64(mk, off);
            mk = (o < mk) ? o : mk;
        }
        if (k == mk) ++p;
        if (lane == 0 && r > 0) IDX[(b * NP + n) * KNB + (r - 1)] = (int)(mk & 0xFFFFFFFFu);
    }
}

// ---------------- cos_angle ----------------
__global__ void cosangle_kernel(const float* __restrict__ coords, const int* __restrict__ IDX,
                                float* __restrict__ COSA) {
    int i = blockIdx.x * 256 + threadIdx.x;
    if (i >= BN * NP * KNB) return;
    int n = (i / KNB) % NP, b = i / (KNB * NP);
    int j = clampj(IDX[i]);
    float xc = coords[(b * 2 + 0) * NP + n], yc = coords[(b * 2 + 1) * NP + n];
    float xm = coords[(b * 2 + 0) * NP + j], ym = coords[(b * 2 + 1) * NP + j];
    float dot = xc * xm + yc * ym;
    float na = sqrtf(xc * xc + yc * yc);
    float nb2 = sqrtf(xm * xm + ym * ym);
    COSA[i] = dot / fmaxf(na * nb2, 1e-30f);
}

// ---------------- convA: 8 pts/block, 256 threads (two halves of 4 pts), fused stats ----------------
__global__ __launch_bounds__(256) void convA_kernel(const float* __restrict__ Fin,
                             const int* __restrict__ IDX,
                             const float* __restrict__ WT, float* __restrict__ YA,
                             float* __restrict__ PART) {
    __shared__ float ctr[CA_PTS][CH];      // 4 KB
    __shared__ float nb[CA_PTS][9][CH];    // 36 KB
    __shared__ int jidx[CA_PTS * 9];
    int b = blockIdx.x / (NP / CA_PTS);
    int chunk = blockIdx.x % (NP / CA_PTS);
    int n0 = chunk * CA_PTS;
    int co = threadIdx.x & 127;
    int half = threadIdx.x >> 7;
    if (threadIdx.x < CA_PTS * 9) {
        int n = threadIdx.x / 9, kk = threadIdx.x % 9;
        jidx[threadIdx.x] = clampj(IDX[(b * NP + n0 + n) * KNB + kk]);
    }
    __syncthreads();
    for (int n = half; n < CA_PTS; n += 2)
        ctr[n][co] = Fin[(b * NP + n0 + n) * CH + co];
    for (int v = half; v < CA_PTS * 9; v += 2)
        nb[v / 9][v % 9][co] = Fin[(b * NP + jidx[v]) * CH + co];
    __syncthreads();
    const int nbase = half * 4;
    float cacc[4] = {0.f, 0.f, 0.f, 0.f};
    for (int ci = 0; ci < CH; ci++) {
        float w = WT[ci * CH + co];
        #pragma unroll
        for (int q = 0; q < 4; q++) cacc[q] += w * ctr[nbase + q][ci];
    }
    float acc[4][3];
    #pragma unroll
    for (int q = 0; q < 4; q++)
        #pragma unroll
        for (int t = 0; t < 3; t++) acc[q][t] = cacc[q];
    for (int dk = 0; dk < 3; dk++) {
        const float* Wd = WT + (1 + dk) * CH * CH;
        for (int ci = 0; ci < CH; ci++) {
            float w = Wd[ci * CH + co];
            #pragma unroll
            for (int q = 0; q < 4; q++)
                #pragma unroll
                for (int t = 0; t < 3; t++)
                    acc[q][t] += w * nb[nbase + q][t * 3 + dk][ci];
        }
    }
    float sum = 0.f, sq = 0.f;
    #pragma unroll
    for (int q = 0; q < 4; q++)
        #pragma unroll
        for (int t = 0; t < 3; t++) {
            float v = acc[q][t];
            YA[((b * NP + n0 + nbase + q) * 3 + t) * CH + co] = v;
            sum += v; sq += v * v;
        }
    int ch2 = chunk * 2 + half;   // nch = NP/CA_PTS*2 = 1024
    PART[((b * (NP / CA_PTS * 2) + ch2) * 256 + co) * 2 + 0] = sum;
    PART[((b * (NP / CA_PTS * 2) + ch2) * 256 + co) * 2 + 1] = sq;
}

// ---------------- angle convA (fused stats partials; nch = NP/32 = 128) ----------------
__global__ void angA_kernel(const float* __restrict__ COSA, const float* __restrict__ WT,
                            float* __restrict__ YA, float* __restrict__ PART) {
    __shared__ float ca[32][10];
    int b = blockIdx.x / (NP / 32);
    int chunk = blockIdx.x % (NP / 32);
    int n0 = chunk * 32;
    int co = threadIdx.x;
    for (int v = threadIdx.x; v < 320; v += 128) {
        int nn = v / 10, kk = v % 10;
        ca[nn][kk] = COSA[(b * NP + n0 + nn) * KNB + kk];
    }
    float w0 = WT[co], w1 = WT[CH + co], w2 = WT[2 * CH + co];
    __syncthreads();
    float sum = 0.f, sq = 0.f;
    for (int nn = 0; nn < 32; nn++) {
        #pragma unroll
        for (int t = 0; t < 3; t++) {
            float v = w0 * ca[nn][3 * t] + w1 * ca[nn][3 * t + 1] + w2 * ca[nn][3 * t + 2];
            YA[((b * NP + n0 + nn) * 3 + t) * CH + co] = v;
            sum += v; sq += v * v;
        }
    }
    PART[((b * (NP / 32) + chunk) * 256 + co) * 2 + 0] = sum;
    PART[((b * (NP / 32) + chunk) * 256 + co) * 2 + 1] = sq;
}

// ---------------- per-pixel GEMM: optional fused input norm+relu, optional output stats ----------------
__global__ void pixel_gemm(const float* __restrict__ IN_, const float* __restrict__ WT,
                           float* __restrict__ OUT, int Cin, int Cout,
                           const float* __restrict__ STATS, int slot,
                           float* __restrict__ PART) {
    extern __shared__ float ldsin[];
    int b = blockIdx.x / (NP / 8);
    int chunk = blockIdx.x % (NP / 8);
    int n0 = chunk * 8;
    int co = threadIdx.x;
    if (slot >= 0) {
        for (int v = threadIdx.x; v < 8 * Cin; v += blockDim.x) {
            int c = v & 127;
            float m = STATS[((slot * BN + b) * 256 + c) * 2 + 0];
            float r = STATS[((slot * BN + b) * 256 + c) * 2 + 1];
            float x = (IN_[(size_t)(b * NP + n0) * Cin + v] - m) * r;
            ldsin[v] = fmaxf(x, 0.f);
        }
    } else {
        for (int v = threadIdx.x; v < 8 * Cin; v += blockDim.x)
            ldsin[v] = IN_[(size_t)(b * NP + n0) * Cin + v];
    }
    __syncthreads();
    float acc[8] = {0.f, 0.f, 0.f, 0.f, 0.f, 0.f, 0.f, 0.f};
    for (int ci = 0; ci < Cin; ci++) {
        float w = WT[ci * Cout + co];
        #pragma unroll
        for (int nn = 0; nn < 8; nn++) acc[nn] += w * ldsin[nn * Cin + ci];
    }
    float sum = 0.f, sq = 0.f;
    #pragma unroll
    for (int nn = 0; nn < 8; nn++) {
        OUT[(size_t)(b * NP + n0 + nn) * Cout + co] = acc[nn];
        sum += acc[nn]; sq += acc[nn] * acc[nn];
    }
    if (PART) {   // nch = NP/8 = 512
        PART[((b * (NP / 8) + chunk) * 256 + co) * 2 + 0] = sum;
        PART[((b * (NP / 8) + chunk) * 256 + co) * 2 + 1] = sq;
    }
}

// ---------------- stats finalize ----------------
__global__ void stats_final(const float* __restrict__ PART, float* __restrict__ STATS,
                            int S, int Cc, int slot, int nch) {
    int i = blockIdx.x * 256 + threadIdx.x;
    if (i >= BN * Cc) return;
    int b = i / Cc, c = i % Cc;
    float sum = 0.f, sq = 0.f;
    for (int ch = 0; ch < nch; ch++) {
        sum += PART[((b * nch + ch) * 256 + c) * 2 + 0];
        sq  += PART[((b * nch + ch) * 256 + c) * 2 + 1];
    }
    float mean = sum / (float)S;
    float var = fmaxf(sq / (float)S - mean * mean, 0.f);
    float rstd = rsqrtf(var + EPSI);
    STATS[((slot * BN + b) * 256 + c) * 2 + 0] = mean;
    STATS[((slot * BN + b) * 256 + c) * 2 + 1] = rstd;
}

// act: 0 = relu, 1 = leaky-relu 0.2
__global__ void norm_act(float* __restrict__ X, const float* __restrict__ STATS,
                         int S, int Cc, int slot, int act) {
    int i = blockIdx.x * 256 + threadIdx.x;
    if (i >= BN * S * Cc) return;
    int c = i % Cc;
    int b = i / (S * Cc);
    float m = STATS[((slot * BN + b) * 256 + c) * 2 + 0];
    float r = STATS[((slot * BN + b) * 256 + c) * 2 + 1];
    float v = (X[i] - m) * r;
    if (act == 0) v = fmaxf(v, 0.f);
    else v = (v >= 0.f) ? v : 0.2f * v;
    X[i] = v;
}

// ---------------- fused U-GEMM + gather + max + stats (16 pts/block; nch = NP/16 = 256) ----------------
__global__ void gathermax_fused(const float* __restrict__ X, const float* __restrict__ Wu,
                                const float* __restrict__ V, const int* __restrict__ IDX,
                                float* __restrict__ M, float* __restrict__ PART, int Cout) {
    __shared__ float rows[GM_PTS * CH];
    int b = blockIdx.x / (NP / GM_PTS);
    int chunk = blockIdx.x % (NP / GM_PTS);
    int n0 = chunk * GM_PTS;
    int c = threadIdx.x;
    for (int v = threadIdx.x; v < GM_PTS * CH; v += blockDim.x)
        rows[v] = X[(size_t)(b * NP + n0) * CH + v];
    __syncthreads();
    float acc[GM_PTS];
    #pragma unroll
    for (int nn = 0; nn < GM_PTS; nn++) acc[nn] = 0.f;
    for (int ci = 0; ci < CH; ci++) {
        float w = Wu[ci * Cout + c];
        #pragma unroll
        for (int nn = 0; nn < GM_PTS; nn++) acc[nn] += w * rows[nn * CH + ci];
    }
    float sum = 0.f, sq = 0.f;
    for (int nn = 0; nn < GM_PTS; nn++) {
        float u = acc[nn];
        float best = -3.4e38f;
        for (int k = 0; k < KNB; k++) {
            int j = clampj(IDX[(b * NP + n0 + nn) * KNB + k]);
            float v = u + V[(size_t)(b * NP + j) * Cout + c];
            sum += v; sq += v * v;
            best = fmaxf(best, v);
        }
        M[(size_t)(b * NP + n0 + nn) * Cout + c] = best;
    }
    PART[((b * (NP / GM_PTS) + chunk) * 256 + c) * 2 + 0] = sum;
    PART[((b * (NP / GM_PTS) + chunk) * 256 + c) * 2 + 1] = sq;
}

// ---------------- heads (fused output stats; nch = NP/8 = 512) ----------------
__global__ void head3_kernel(const float* __restrict__ F, const float* __restrict__ X1,
                             const float* __restrict__ X2, const float* __restrict__ FANG,
                             const float* __restrict__ WT, float* __restrict__ Y3,
                             float* __restrict__ PART) {
    __shared__ float lds[8 * 384];
    int b = blockIdx.x / (NP / 8);
    int chunk = blockIdx.x % (NP / 8);
    int n0 = chunk * 8;
    int co = threadIdx.x;
    for (int v = threadIdx.x; v < 8 * 384; v += 128) {
        int nn = v / 384, q = v % 384;
        int part = q / 128, ci = q % 128;
        size_t base = (size_t)(b * NP + n0 + nn) * CH + ci;
        float val;
        if (part == 0) val = F[base];
        else if (part == 1) val = X1[base] + FANG[base];
        else val = X2[base] + FANG[base];
        lds[v] = val;
    }
    __syncthreads();
    float acc[8] = {0.f, 0.f, 0.f, 0.f, 0.f, 0.f, 0.f, 0.f};
    for (int ci = 0; ci < 384; ci++) {
        float w = WT[ci * CH + co];
        #pragma unroll
        for (int nn = 0; nn < 8; nn++) acc[nn] += w * lds[nn * 384 + ci];
    }
    float sum = 0.f, sq = 0.f;
    #pragma unroll
    for (int nn = 0; nn < 8; nn++) {
        Y3[(size_t)(b * NP + n0 + nn) * CH + co] = acc[nn];
        sum += acc[nn]; sq += acc[nn] * acc[nn];
    }
    PART[((b * (NP / 8) + chunk) * 256 + co) * 2 + 0] = sum;
    PART[((b * (NP / 8) + chunk) * 256 + co) * 2 + 1] = sq;
}

__global__ void head3o_kernel(const float* __restrict__ F, const float* __restrict__ X1O,
                              const float* __restrict__ X2O, const float* __restrict__ WT,
                              float* __restrict__ Y3O, float* __restrict__ PART) {
    __shared__ float lds[8 * 512];
    int b = blockIdx.x / (NP / 8);
    int chunk = blockIdx.x % (NP / 8);
    int n0 = chunk * 8;
    int co = threadIdx.x;
    for (int v = threadIdx.x; v < 8 * 512; v += 128) {
        int nn = v / 512, q = v % 512;
        float val;
        if (q < 128) val = F[(size_t)(b * NP + n0 + nn) * CH + q];
        else if (q < 256) val = X1O[(size_t)(b * NP + n0 + nn) * CH + (q - 128)];
        else val = X2O[(size_t)(b * NP + n0 + nn) * 256 + (q - 256)];
        lds[v] = val;
    }
    __syncthreads();
    float acc[8] = {0.f, 0.f, 0.f, 0.f, 0.f, 0.f, 0.f, 0.f};
    for (int ci = 0; ci < 512; ci++) {
        float w = WT[ci * CH + co];
        #pragma unroll
        for (int nn = 0; nn < 8; nn++) acc[nn] += w * lds[nn * 512 + ci];
    }
    float sum = 0.f, sq = 0.f;
    #pragma unroll
    for (int nn = 0; nn < 8; nn++) {
        Y3O[(size_t)(b * NP + n0 + nn) * CH + co] = acc[nn];
        sum += acc[nn]; sq += acc[nn] * acc[nn];
    }
    PART[((b * (NP / 8) + chunk) * 256 + co) * 2 + 0] = sum;
    PART[((b * (NP / 8) + chunk) * 256 + co) * 2 + 1] = sq;
}

// ---------------- final ----------------
__global__ void final_kernel(const float* __restrict__ Y3, const float* __restrict__ Y3O,
                             const float* __restrict__ STATS, float* __restrict__ out) {
    __shared__ float T[64][129];
    int b = blockIdx.x / (NP / 64);
    int n0 = (blockIdx.x % (NP / 64)) * 64;
    int co = threadIdx.x;
    float m3 = STATS[((8 * BN + b) * 256 + co) * 2 + 0];
    float r3 = STATS[((8 * BN + b) * 256 + co) * 2 + 1];
    float m3o = STATS[((9 * BN + b) * 256 + co) * 2 + 0];
    float r3o = STATS[((9 * BN + b) * 256 + co) * 2 + 1];
    for (int j = 0; j < 64; j++) {
        size_t idx = (size_t)(b * NP + n0 + j) * CH + co;
        float v3 = (Y3[idx] - m3) * r3;
        v3 = (v3 >= 0.f) ? v3 : 0.2f * v3;
        float v3o = (Y3O[idx] - m3o) * r3o;
        v3o = (v3o >= 0.f) ? v3o : 0.2f * v3o;
        T[j][co] = v3 + v3o;
    }
    __syncthreads();
    for (int rr = 0; rr < 64; rr++) {
        int r = rr * 2 + (threadIdx.x >> 6);
        int j = threadIdx.x & 63;
        out[(size_t)(b * CH + r) * NP + n0 + j] = T[j][r];
    }
}

// ---------------- launch ----------------
extern "C" void kernel_launch(void* const* d_in, const int* in_sizes, int n_in,
                              void* d_out, int out_size, void* d_ws, size_t ws_size,
                              hipStream_t stream) {
    const float* coords   = (const float*)d_in[0];
    const float* features = (const float*)d_in[1];
    const float* W1   = (const float*)d_in[2];
    const float* W2   = (const float*)d_in[3];
    const float* W3   = (const float*)d_in[4];
    const float* W3o  = (const float*)d_in[5];
    const float* a1wA = (const float*)d_in[6];
    const float* a1wB = (const float*)d_in[8];
    const float* a2wA = (const float*)d_in[10];
    const float* a2wB = (const float*)d_in[12];
    const float* angwA = (const float*)d_in[14];
    const float* angwB = (const float*)d_in[16];
    float* out = (float*)d_out;
    float* ws = (float*)d_ws;
    (void)ws_size; (void)in_sizes; (void)n_in; (void)out_size;

    size_t off = 0;
    float* WA1T  = ws + off; off += 4 * CH * CH;
    float* WA2T  = ws + off; off += 4 * CH * CH;
    float* WB1T  = ws + off; off += 3 * CH * CH;
    float* WB2T  = ws + off; off += 3 * CH * CH;
    float* WBAT  = ws + off; off += 3 * CH * CH;
    float* WANGA = ws + off; off += 512;
    float* W1U   = ws + off; off += CH * CH;
    float* W1N   = ws + off; off += CH * CH;
    float* W2U   = ws + off; off += CH * 256;
    float* W2N   = ws + off; off += CH * 256;
    float* W3T   = ws + off; off += 384 * CH;
    float* W3OT  = ws + off; off += 512 * CH;
    int*   IDX   = (int*)(ws + off); off += (size_t)BN * NP * KNB;
    float* COSA  = ws + off; off += (size_t)BN * NP * KNB;
    float* PART  = ws + off; off += (size_t)BN * 1024 * 256 * 2;  // 8 MB (max nch=1024)
    float* STATS = ws + off; off += 10 * BN * 256 * 2;
    const size_t UNIT = (size_t)BN * NP * CH;
    float* POOL  = ws + off; off += 7 * UNIT;

    float* F    = POOL + 0 * UNIT;
    float* YA   = POOL + 1 * UNIT;  // slots 1-3
    float* X1   = POOL + 4 * UNIT;
    float* FANG = POOL + 5 * UNIT;
    float* X2   = POOL + 6 * UNIT;
    float* Y3   = POOL + 1 * UNIT;  // slot 1 (YA dead)
    float* V1   = POOL + 2 * UNIT;  // slot 2
    float* M1   = POOL + 6 * UNIT;  // slot 6 (X2 dead)  -> X1O
    float* V2   = POOL + 4 * UNIT;  // slots 4-5 (X1,FANG dead)
    float* M2   = POOL + 2 * UNIT;  // slots 2-3 (V1 dead) -> X2O
    float* Y3O  = POOL + 4 * UNIT;  // slot 4 (V2 dead)

    pack_convA<<<(4 * CH * CH + 255) / 256, 256, 0, stream>>>(a1wA, WA1T);
    pack_convA<<<(4 * CH * CH + 255) / 256, 256, 0, stream>>>(a2wA, WA2T);
    pack_convB<<<(3 * CH * CH + 255) / 256, 256, 0, stream>>>(a1wB, WB1T);
    pack_convB<<<(3 * CH * CH + 255) / 256, 256, 0, stream>>>(a2wB, WB2T);
    pack_convB<<<(3 * CH * CH + 255) / 256, 256, 0, stream>>>(angwB, WBAT);
    pack_uv<<<(CH * CH + 255) / 256, 256, 0, stream>>>(W1, W1U, W1N, CH);
    pack_uv<<<(CH * 256 + 255) / 256, 256, 0, stream>>>(W2, W2U, W2N, 256);
    pack_plain<<<(384 * CH + 255) / 256, 256, 0, stream>>>(W3, W3T, 384, CH);
    pack_plain<<<(512 * CH + 255) / 256, 256, 0, stream>>>(W3o, W3OT, 512, CH);
    pack_plain<<<(3 * CH + 255) / 256, 256, 0, stream>>>(angwA, WANGA, 3, CH);

    ftrans_kernel<<<(BN * CH * NP + 255) / 256, 256, 0, stream>>>(features, F);
    knn_kernel<<<BN * NP / 4, 256, 0, stream>>>(coords, IDX);
    cosangle_kernel<<<(BN * NP * KNB + 255) / 256, 256, 0, stream>>>(coords, IDX, COSA);

    auto sfin = [&](int S, int Cc, int slot, int nch) {
        stats_final<<<(BN * Cc + 255) / 256, 256, 0, stream>>>(PART, STATS, S, Cc, slot, nch);
    };
    auto norm = [&](float* X, int S, int Cc, int slot, int act) {
        int tot = BN * S * Cc;
        norm_act<<<(tot + 255) / 256, 256, 0, stream>>>(X, STATS, S, Cc, slot, act);
    };

    // --- x1 block ---
    convA_kernel<<<BN * (NP / CA_PTS), 256, 0, stream>>>(F, IDX, WA1T, YA, PART);
    sfin(3 * NP, CH, 0, NP / CA_PTS * 2);
    pixel_gemm<<<BN * (NP / 8), 128, 8 * 384 * 4, stream>>>(YA, WB1T, X1, 384, CH, STATS, 0, PART);
    sfin(NP, CH, 1, NP / 8);
    norm(X1, NP, CH, 1, 0);

    // --- angle block ---
    angA_kernel<<<BN * (NP / 32), 128, 0, stream>>>(COSA, WANGA, YA, PART);
    sfin(3 * NP, CH, 2, NP / 32);
    pixel_gemm<<<BN * (NP / 8), 128, 8 * 384 * 4, stream>>>(YA, WBAT, FANG, 384, CH, STATS, 2, PART);
    sfin(NP, CH, 3, NP / 8);
    norm(FANG, NP, CH, 3, 0);

    // --- x2 block ---
    convA_kernel<<<BN * (NP / CA_PTS), 256, 0, stream>>>(X1, IDX, WA2T, YA, PART);
    sfin(3 * NP, CH, 4, NP / CA_PTS * 2);
    pixel_gemm<<<BN * (NP / 8), 128, 8 * 384 * 4, stream>>>(YA, WB2T, X2, 384, CH, STATS, 4, PART);
    sfin(NP, CH, 5, NP / 8);
    norm(X2, NP, CH, 5, 0);

    // --- head3 ---
    head3_kernel<<<BN * (NP / 8), 128, 0, stream>>>(F, X1, X2, FANG, W3T, Y3, PART);
    sfin(NP, CH, 8, NP / 8);

    // --- x1o path ---
    pixel_gemm<<<BN * (NP / 8), 128, 8 * 128 * 4, stream>>>(F, W1N, V1, 128, CH, STATS, -1, nullptr);
    gathermax_fused<<<BN * (NP / GM_PTS), CH, 0, stream>>>(F, W1U, V1, IDX, M1, PART, CH);
    sfin(NP * KNB, CH, 6, NP / GM_PTS);
    norm(M1, NP, CH, 6, 1);

    // --- x2o path ---
    pixel_gemm<<<BN * (NP / 8), 256, 8 * 128 * 4, stream>>>(M1, W2N, V2, 128, 256, STATS, -1, nullptr);
    gathermax_fused<<<BN * (NP / GM_PTS), 256, 0, stream>>>(M1, W2U, V2, IDX, M2, PART, 256);
    sfin(NP * KNB, 256, 7, NP / GM_PTS);
    norm(M2, NP, 256, 7, 1);

    // --- head3o + final ---
    head3o_kernel<<<BN * (NP / 8), 128, 0, stream>>>(F, M1, M2, W3OT, Y3O, PART);
    sfin(NP, CH, 9, NP / 8);
    final_kernel<<<BN * (NP / 64), 128, 0, stream>>>(Y3, Y3O, STATS, out);
}

// Round 16
// 1045.267 us; speedup vs baseline: 2.3075x; 2.3075x over previous
//
#include <hip/hip_runtime.h>
#include <hip/hip_bf16.h>

typedef unsigned long long ull;

#define BN 4
#define CH 128
#define NP 4096
#define KNB 10
#define EPSI 1e-5f
#define GM_PTS 16
#define CA_PTS 8

__device__ __forceinline__ ull shfl_xor_u64(ull v, int mask) {
    unsigned lo = (unsigned)(v & 0xFFFFFFFFu);
    unsigned hi = (unsigned)(v >> 32);
    lo = __shfl_xor(lo, mask);
    hi = __shfl_xor(hi, mask);
    return ((ull)hi << 32) | lo;
}

__device__ __forceinline__ int clampj(int j) { return ((unsigned)j < (unsigned)NP) ? j : 0; }

// ---------------- weight packing ----------------
__global__ void pack_convA(const float* __restrict__ w, float* __restrict__ WT) {
    int i = blockIdx.x * 256 + threadIdx.x;
    if (i >= 4 * CH * CH) return;
    int co = i % CH, ci = (i / CH) % CH, s = i / (CH * CH);
    float val;
    if (s == 0) {
        val = 0.f;
        for (int dk = 0; dk < 3; dk++)
            val += w[(co * 256 + ci) * 3 + dk] - w[(co * 256 + 128 + ci) * 3 + dk];
    } else {
        val = w[(co * 256 + 128 + ci) * 3 + (s - 1)];
    }
    WT[i] = val;
}

__global__ void pack_convB(const float* __restrict__ w, float* __restrict__ WT) {
    int i = blockIdx.x * 256 + threadIdx.x;
    if (i >= 3 * CH * CH) return;
    int co = i % CH, ci = (i / CH) % CH, dk = i / (CH * CH);
    WT[i] = w[(co * CH + ci) * 3 + dk];
}

__global__ void pack_uv(const float* __restrict__ w, float* __restrict__ WuT,
                        float* __restrict__ WnT, int Cout) {
    int i = blockIdx.x * 256 + threadIdx.x;
    if (i >= Cout * CH) return;
    int co = i % Cout, ci = i / Cout;
    float a = w[co * 256 + ci], b = w[co * 256 + 128 + ci];
    WuT[i] = a - b;
    WnT[i] = b;
}

__global__ void pack_plain(const float* __restrict__ w, float* __restrict__ WT, int Cin, int Cout) {
    int i = blockIdx.x * 256 + threadIdx.x;
    if (i >= Cin * Cout) return;
    int co = i % Cout, ci = i / Cout;
    WT[i] = w[co * Cin + ci];
}

// ---------------- features transpose ----------------
__global__ void ftrans_kernel(const float* __restrict__ feats, float* __restrict__ F) {
    int i = blockIdx.x * 256 + threadIdx.x;
    if (i >= BN * CH * NP) return;
    int n = i % NP, c = (i / NP) % CH, b = i / (NP * CH);
    F[(b * NP + n) * CH + c] = feats[i];
}

// ---------------- KNN ----------------
__global__ void knn_kernel(const float* __restrict__ coords, int* __restrict__ IDX) {
    int gw = blockIdx.x * 4 + (threadIdx.x >> 6);
    int b = gw / NP;
    int n = gw % NP;
    int lane = threadIdx.x & 63;
    float xn = coords[(b * 2 + 0) * NP + n];
    float yn = coords[(b * 2 + 1) * NP + n];
    float sn = __fadd_rn(__fmul_rn(xn, xn), __fmul_rn(yn, yn));
    ull a[11];
    #pragma unroll
    for (int q = 0; q < 11; q++) a[q] = 0xFFFFFFFFFFFFFFFFULL;
    for (int m = lane; m < NP; m += 64) {
        float xm = coords[(b * 2 + 0) * NP + m];
        float ym = coords[(b * 2 + 1) * NP + m];
        float sm = __fadd_rn(__fmul_rn(xm, xm), __fmul_rn(ym, ym));
        float dot = __fmaf_rn(yn, ym, __fmul_rn(xn, xm));
        float d = __fsub_rn(__fadd_rn(sn, sm), __fmul_rn(2.0f, dot));
        d = fmaxf(d, 1e-12f);
        ull key = ((ull)__float_as_uint(d) << 32) | (unsigned)m;
        if (key < a[10]) {
            a[10] = key;
            #pragma unroll
            for (int q = 10; q > 0; --q)
                if (a[q] < a[q - 1]) { ull t = a[q]; a[q] = a[q - 1]; a[q - 1] = t; }
        }
    }
    int p = 0;
    for (int r = 0; r < 11; ++r) {
        ull k = (p < 11) ? a[p] : 0xFFFFFFFFFFFFFFFFULL;
        ull mk = k;
        #pragma unroll
        for (int off = 1; off < 64; off <<= 1) {
            ull o = shfl_xor_u64(mk, off);
            mk = (o < mk) ? o : mk;
        }
        if (k == mk) ++p;
        if (lane == 0 && r > 0) IDX[(b * NP + n) * KNB + (r - 1)] = (int)(mk & 0xFFFFFFFFu);
    }
}

// ---------------- cos_angle ----------------
__global__ void cosangle_kernel(const float* __restrict__ coords, const int* __restrict__ IDX,
                                float* __restrict__ COSA) {
    int i = blockIdx.x * 256 + threadIdx.x;
    if (i >= BN * NP * KNB) return;
    int n = (i / KNB) % NP, b = i / (KNB * NP);
    int j = clampj(IDX[i]);
    float xc = coords[(b * 2 + 0) * NP + n], yc = coords[(b * 2 + 1) * NP + n];
    float xm = coords[(b * 2 + 0) * NP + j], ym = coords[(b * 2 + 1) * NP + j];
    float dot = xc * xm + yc * ym;
    float na = sqrtf(xc * xc + yc * yc);
    float nb2 = sqrtf(xm * xm + ym * ym);
    COSA[i] = dot / fmaxf(na * nb2, 1e-30f);
}

// ---------------- convA: 8 pts/block, 256 threads, fused stats ----------------
__global__ __launch_bounds__(256) void convA_kernel(const float* __restrict__ Fin,
                             const int* __restrict__ IDX,
                             const float* __restrict__ WT, float* __restrict__ YA,
                             float* __restrict__ PART) {
    __shared__ float ctr[CA_PTS][CH];
    __shared__ float nb[CA_PTS][9][CH];
    __shared__ int jidx[CA_PTS * 9];
    int b = blockIdx.x / (NP / CA_PTS);
    int chunk = blockIdx.x % (NP / CA_PTS);
    int n0 = chunk * CA_PTS;
    int co = threadIdx.x & 127;
    int half = threadIdx.x >> 7;
    if (threadIdx.x < CA_PTS * 9) {
        int n = threadIdx.x / 9, kk = threadIdx.x % 9;
        jidx[threadIdx.x] = clampj(IDX[(b * NP + n0 + n) * KNB + kk]);
    }
    __syncthreads();
    for (int n = half; n < CA_PTS; n += 2)
        ctr[n][co] = Fin[(b * NP + n0 + n) * CH + co];
    for (int v = half; v < CA_PTS * 9; v += 2)
        nb[v / 9][v % 9][co] = Fin[(b * NP + jidx[v]) * CH + co];
    __syncthreads();
    const int nbase = half * 4;
    float cacc[4] = {0.f, 0.f, 0.f, 0.f};
    for (int ci = 0; ci < CH; ci++) {
        float w = WT[ci * CH + co];
        #pragma unroll
        for (int q = 0; q < 4; q++) cacc[q] += w * ctr[nbase + q][ci];
    }
    float acc[4][3];
    #pragma unroll
    for (int q = 0; q < 4; q++)
        #pragma unroll
        for (int t = 0; t < 3; t++) acc[q][t] = cacc[q];
    for (int dk = 0; dk < 3; dk++) {
        const float* Wd = WT + (1 + dk) * CH * CH;
        for (int ci = 0; ci < CH; ci++) {
            float w = Wd[ci * CH + co];
            #pragma unroll
            for (int q = 0; q < 4; q++)
                #pragma unroll
                for (int t = 0; t < 3; t++)
                    acc[q][t] += w * nb[nbase + q][t * 3 + dk][ci];
        }
    }
    float sum = 0.f, sq = 0.f;
    #pragma unroll
    for (int q = 0; q < 4; q++)
        #pragma unroll
        for (int t = 0; t < 3; t++) {
            float v = acc[q][t];
            YA[((b * NP + n0 + nbase + q) * 3 + t) * CH + co] = v;
            sum += v; sq += v * v;
        }
    int ch2 = chunk * 2 + half;   // nch = 1024
    PART[((b * (NP / CA_PTS * 2) + ch2) * 256 + co) * 2 + 0] = sum;
    PART[((b * (NP / CA_PTS * 2) + ch2) * 256 + co) * 2 + 1] = sq;
}

// ---------------- angle convA (nch = 128) ----------------
__global__ void angA_kernel(const float* __restrict__ COSA, const float* __restrict__ WT,
                            float* __restrict__ YA, float* __restrict__ PART) {
    __shared__ float ca[32][10];
    int b = blockIdx.x / (NP / 32);
    int chunk = blockIdx.x % (NP / 32);
    int n0 = chunk * 32;
    int co = threadIdx.x;
    for (int v = threadIdx.x; v < 320; v += 128) {
        int nn = v / 10, kk = v % 10;
        ca[nn][kk] = COSA[(b * NP + n0 + nn) * KNB + kk];
    }
    float w0 = WT[co], w1 = WT[CH + co], w2 = WT[2 * CH + co];
    __syncthreads();
    float sum = 0.f, sq = 0.f;
    for (int nn = 0; nn < 32; nn++) {
        #pragma unroll
        for (int t = 0; t < 3; t++) {
            float v = w0 * ca[nn][3 * t] + w1 * ca[nn][3 * t + 1] + w2 * ca[nn][3 * t + 2];
            YA[((b * NP + n0 + nn) * 3 + t) * CH + co] = v;
            sum += v; sq += v * v;
        }
    }
    PART[((b * (NP / 32) + chunk) * 256 + co) * 2 + 0] = sum;
    PART[((b * (NP / 32) + chunk) * 256 + co) * 2 + 1] = sq;
}

// ---------------- per-pixel GEMM: fused input norm+relu, optional output stats ----------------
__global__ void pixel_gemm(const float* __restrict__ IN_, const float* __restrict__ WT,
                           float* __restrict__ OUT, int Cin, int Cout,
                           const float* __restrict__ STATS, int slot,
                           float* __restrict__ PART) {
    extern __shared__ float ldsin[];
    int b = blockIdx.x / (NP / 8);
    int chunk = blockIdx.x % (NP / 8);
    int n0 = chunk * 8;
    int co = threadIdx.x;
    if (slot >= 0) {
        for (int v = threadIdx.x; v < 8 * Cin; v += blockDim.x) {
            int c = v & 127;
            float m = STATS[((slot * BN + b) * 256 + c) * 2 + 0];
            float r = STATS[((slot * BN + b) * 256 + c) * 2 + 1];
            float x = (IN_[(size_t)(b * NP + n0) * Cin + v] - m) * r;
            ldsin[v] = fmaxf(x, 0.f);
        }
    } else {
        for (int v = threadIdx.x; v < 8 * Cin; v += blockDim.x)
            ldsin[v] = IN_[(size_t)(b * NP + n0) * Cin + v];
    }
    __syncthreads();
    float acc[8] = {0.f, 0.f, 0.f, 0.f, 0.f, 0.f, 0.f, 0.f};
    for (int ci = 0; ci < Cin; ci++) {
        float w = WT[ci * Cout + co];
        #pragma unroll
        for (int nn = 0; nn < 8; nn++) acc[nn] += w * ldsin[nn * Cin + ci];
    }
    float sum = 0.f, sq = 0.f;
    #pragma unroll
    for (int nn = 0; nn < 8; nn++) {
        OUT[(size_t)(b * NP + n0 + nn) * Cout + co] = acc[nn];
        sum += acc[nn]; sq += acc[nn] * acc[nn];
    }
    if (PART) {   // nch = 512
        PART[((b * (NP / 8) + chunk) * 256 + co) * 2 + 0] = sum;
        PART[((b * (NP / 8) + chunk) * 256 + co) * 2 + 1] = sq;
    }
}

// ---------------- stats finalize: one block per (b,c), parallel tree reduce ----------------
__global__ void stats_final(const float* __restrict__ PART, float* __restrict__ STATS,
                            int S, int Cc, int slot, int nch) {
    __shared__ float ssum[256], ssq[256];
    int bc = blockIdx.x;          // b*Cc + c
    int b = bc / Cc, c = bc % Cc;
    float sum = 0.f, sq = 0.f;
    for (int ch = threadIdx.x; ch < nch; ch += 256) {
        sum += PART[((b * nch + ch) * 256 + c) * 2 + 0];
        sq  += PART[((b * nch + ch) * 256 + c) * 2 + 1];
    }
    ssum[threadIdx.x] = sum; ssq[threadIdx.x] = sq;
    __syncthreads();
    for (int s = 128; s > 0; s >>= 1) {
        if (threadIdx.x < s) {
            ssum[threadIdx.x] += ssum[threadIdx.x + s];
            ssq[threadIdx.x]  += ssq[threadIdx.x + s];
        }
        __syncthreads();
    }
    if (threadIdx.x == 0) {
        float mean = ssum[0] / (float)S;
        float var = fmaxf(ssq[0] / (float)S - mean * mean, 0.f);
        STATS[((slot * BN + b) * 256 + c) * 2 + 0] = mean;
        STATS[((slot * BN + b) * 256 + c) * 2 + 1] = rsqrtf(var + EPSI);
    }
}

// act: 0 = relu, 1 = leaky-relu 0.2
__global__ void norm_act(float* __restrict__ X, const float* __restrict__ STATS,
                         int S, int Cc, int slot, int act) {
    int i = blockIdx.x * 256 + threadIdx.x;
    if (i >= BN * S * Cc) return;
    int c = i % Cc;
    int b = i / (S * Cc);
    float m = STATS[((slot * BN + b) * 256 + c) * 2 + 0];
    float r = STATS[((slot * BN + b) * 256 + c) * 2 + 1];
    float v = (X[i] - m) * r;
    if (act == 0) v = fmaxf(v, 0.f);
    else v = (v >= 0.f) ? v : 0.2f * v;
    X[i] = v;
}

// ---------------- fused U-GEMM + gather + max + stats (nch = 256) ----------------
__global__ void gathermax_fused(const float* __restrict__ X, const float* __restrict__ Wu,
                                const float* __restrict__ V, const int* __restrict__ IDX,
                                float* __restrict__ M, float* __restrict__ PART, int Cout) {
    __shared__ float rows[GM_PTS * CH];
    int b = blockIdx.x / (NP / GM_PTS);
    int chunk = blockIdx.x % (NP / GM_PTS);
    int n0 = chunk * GM_PTS;
    int c = threadIdx.x;
    for (int v = threadIdx.x; v < GM_PTS * CH; v += blockDim.x)
        rows[v] = X[(size_t)(b * NP + n0) * CH + v];
    __syncthreads();
    float acc[GM_PTS];
    #pragma unroll
    for (int nn = 0; nn < GM_PTS; nn++) acc[nn] = 0.f;
    for (int ci = 0; ci < CH; ci++) {
        float w = Wu[ci * Cout + c];
        #pragma unroll
        for (int nn = 0; nn < GM_PTS; nn++) acc[nn] += w * rows[nn * CH + ci];
    }
    float sum = 0.f, sq = 0.f;
    for (int nn = 0; nn < GM_PTS; nn++) {
        float u = acc[nn];
        float best = -3.4e38f;
        for (int k = 0; k < KNB; k++) {
            int j = clampj(IDX[(b * NP + n0 + nn) * KNB + k]);
            float v = u + V[(size_t)(b * NP + j) * Cout + c];
            sum += v; sq += v * v;
            best = fmaxf(best, v);
        }
        M[(size_t)(b * NP + n0 + nn) * Cout + c] = best;
    }
    PART[((b * (NP / GM_PTS) + chunk) * 256 + c) * 2 + 0] = sum;
    PART[((b * (NP / GM_PTS) + chunk) * 256 + c) * 2 + 1] = sq;
}

// ---------------- heads (fused output stats; nch = 512) ----------------
__global__ void head3_kernel(const float* __restrict__ F, const float* __restrict__ X1,
                             const float* __restrict__ X2, const float* __restrict__ FANG,
                             const float* __restrict__ WT, float* __restrict__ Y3,
                             float* __restrict__ PART) {
    __shared__ float lds[8 * 384];
    int b = blockIdx.x / (NP / 8);
    int chunk = blockIdx.x % (NP / 8);
    int n0 = chunk * 8;
    int co = threadIdx.x;
    for (int v = threadIdx.x; v < 8 * 384; v += 128) {
        int nn = v / 384, q = v % 384;
        int part = q / 128, ci = q % 128;
        size_t base = (size_t)(b * NP + n0 + nn) * CH + ci;
        float val;
        if (part == 0) val = F[base];
        else if (part == 1) val = X1[base] + FANG[base];
        else val = X2[base] + FANG[base];
        lds[v] = val;
    }
    __syncthreads();
    float acc[8] = {0.f, 0.f, 0.f, 0.f, 0.f, 0.f, 0.f, 0.f};
    for (int ci = 0; ci < 384; ci++) {
        float w = WT[ci * CH + co];
        #pragma unroll
        for (int nn = 0; nn < 8; nn++) acc[nn] += w * lds[nn * 384 + ci];
    }
    float sum = 0.f, sq = 0.f;
    #pragma unroll
    for (int nn = 0; nn < 8; nn++) {
        Y3[(size_t)(b * NP + n0 + nn) * CH + co] = acc[nn];
        sum += acc[nn]; sq += acc[nn] * acc[nn];
    }
    PART[((b * (NP / 8) + chunk) * 256 + co) * 2 + 0] = sum;
    PART[((b * (NP / 8) + chunk) * 256 + co) * 2 + 1] = sq;
}

__global__ void head3o_kernel(const float* __restrict__ F, const float* __restrict__ X1O,
                              const float* __restrict__ X2O, const float* __restrict__ WT,
                              float* __restrict__ Y3O, float* __restrict__ PART) {
    __shared__ float lds[8 * 512];
    int b = blockIdx.x / (NP / 8);
    int chunk = blockIdx.x % (NP / 8);
    int n0 = chunk * 8;
    int co = threadIdx.x;
    for (int v = threadIdx.x; v < 8 * 512; v += 128) {
        int nn = v / 512, q = v % 512;
        float val;
        if (q < 128) val = F[(size_t)(b * NP + n0 + nn) * CH + q];
        else if (q < 256) val = X1O[(size_t)(b * NP + n0 + nn) * CH + (q - 128)];
        else val = X2O[(size_t)(b * NP + n0 + nn) * 256 + (q - 256)];
        lds[v] = val;
    }
    __syncthreads();
    float acc[8] = {0.f, 0.f, 0.f, 0.f, 0.f, 0.f, 0.f, 0.f};
    for (int ci = 0; ci < 512; ci++) {
        float w = WT[ci * CH + co];
        #pragma unroll
        for (int nn = 0; nn < 8; nn++) acc[nn] += w * lds[nn * 512 + ci];
    }
    float sum = 0.f, sq = 0.f;
    #pragma unroll
    for (int nn = 0; nn < 8; nn++) {
        Y3O[(size_t)(b * NP + n0 + nn) * CH + co] = acc[nn];
        sum += acc[nn]; sq += acc[nn] * acc[nn];
    }
    PART[((b * (NP / 8) + chunk) * 256 + co) * 2 + 0] = sum;
    PART[((b * (NP / 8) + chunk) * 256 + co) * 2 + 1] = sq;
}

// ---------------- final ----------------
__global__ void final_kernel(const float* __restrict__ Y3, const float* __restrict__ Y3O,
                             const float* __restrict__ STATS, float* __restrict__ out) {
    __shared__ float T[64][129];
    int b = blockIdx.x / (NP / 64);
    int n0 = (blockIdx.x % (NP / 64)) * 64;
    int co = threadIdx.x;
    float m3 = STATS[((8 * BN + b) * 256 + co) * 2 + 0];
    float r3 = STATS[((8 * BN + b) * 256 + co) * 2 + 1];
    float m3o = STATS[((9 * BN + b) * 256 + co) * 2 + 0];
    float r3o = STATS[((9 * BN + b) * 256 + co) * 2 + 1];
    for (int j = 0; j < 64; j++) {
        size_t idx = (size_t)(b * NP + n0 + j) * CH + co;
        float v3 = (Y3[idx] - m3) * r3;
        v3 = (v3 >= 0.f) ? v3 : 0.2f * v3;
        float v3o = (Y3O[idx] - m3o) * r3o;
        v3o = (v3o >= 0.f) ? v3o : 0.2f * v3o;
        T[j][co] = v3 + v3o;
    }
    __syncthreads();
    for (int rr = 0; rr < 64; rr++) {
        int r = rr * 2 + (threadIdx.x >> 6);
        int j = threadIdx.x & 63;
        out[(size_t)(b * CH + r) * NP + n0 + j] = T[j][r];
    }
}

// ---------------- launch ----------------
extern "C" void kernel_launch(void* const* d_in, const int* in_sizes, int n_in,
                              void* d_out, int out_size, void* d_ws, size_t ws_size,
                              hipStream_t stream) {
    const float* coords   = (const float*)d_in[0];
    const float* features = (const float*)d_in[1];
    const float* W1   = (const float*)d_in[2];
    const float* W2   = (const float*)d_in[3];
    const float* W3   = (const float*)d_in[4];
    const float* W3o  = (const float*)d_in[5];
    const float* a1wA = (const float*)d_in[6];
    const float* a1wB = (const float*)d_in[8];
    const float* a2wA = (const float*)d_in[10];
    const float* a2wB = (const float*)d_in[12];
    const float* angwA = (const float*)d_in[14];
    const float* angwB = (const float*)d_in[16];
    float* out = (float*)d_out;
    float* ws = (float*)d_ws;
    (void)ws_size; (void)in_sizes; (void)n_in; (void)out_size;

    size_t off = 0;
    float* WA1T  = ws + off; off += 4 * CH * CH;
    float* WA2T  = ws + off; off += 4 * CH * CH;
    float* WB1T  = ws + off; off += 3 * CH * CH;
    float* WB2T  = ws + off; off += 3 * CH * CH;
    float* WBAT  = ws + off; off += 3 * CH * CH;
    float* WANGA = ws + off; off += 512;
    float* W1U   = ws + off; off += CH * CH;
    float* W1N   = ws + off; off += CH * CH;
    float* W2U   = ws + off; off += CH * 256;
    float* W2N   = ws + off; off += CH * 256;
    float* W3T   = ws + off; off += 384 * CH;
    float* W3OT  = ws + off; off += 512 * CH;
    int*   IDX   = (int*)(ws + off); off += (size_t)BN * NP * KNB;
    float* COSA  = ws + off; off += (size_t)BN * NP * KNB;
    float* PART  = ws + off; off += (size_t)BN * 1024 * 256 * 2;
    float* STATS = ws + off; off += 10 * BN * 256 * 2;
    const size_t UNIT = (size_t)BN * NP * CH;
    float* POOL  = ws + off; off += 7 * UNIT;

    float* F    = POOL + 0 * UNIT;
    float* YA   = POOL + 1 * UNIT;  // slots 1-3
    float* X1   = POOL + 4 * UNIT;
    float* FANG = POOL + 5 * UNIT;
    float* X2   = POOL + 6 * UNIT;
    float* Y3   = POOL + 1 * UNIT;  // slot 1 (YA dead)
    float* V1   = POOL + 2 * UNIT;  // slot 2
    float* M1   = POOL + 6 * UNIT;  // slot 6 (X2 dead)  -> X1O
    float* V2   = POOL + 4 * UNIT;  // slots 4-5 (X1,FANG dead)
    float* M2   = POOL + 2 * UNIT;  // slots 2-3 (V1 dead) -> X2O
    float* Y3O  = POOL + 4 * UNIT;  // slot 4 (V2 dead)

    pack_convA<<<(4 * CH * CH + 255) / 256, 256, 0, stream>>>(a1wA, WA1T);
    pack_convA<<<(4 * CH * CH + 255) / 256, 256, 0, stream>>>(a2wA, WA2T);
    pack_convB<<<(3 * CH * CH + 255) / 256, 256, 0, stream>>>(a1wB, WB1T);
    pack_convB<<<(3 * CH * CH + 255) / 256, 256, 0, stream>>>(a2wB, WB2T);
    pack_convB<<<(3 * CH * CH + 255) / 256, 256, 0, stream>>>(angwB, WBAT);
    pack_uv<<<(CH * CH + 255) / 256, 256, 0, stream>>>(W1, W1U, W1N, CH);
    pack_uv<<<(CH * 256 + 255) / 256, 256, 0, stream>>>(W2, W2U, W2N, 256);
    pack_plain<<<(384 * CH + 255) / 256, 256, 0, stream>>>(W3, W3T, 384, CH);
    pack_plain<<<(512 * CH + 255) / 256, 256, 0, stream>>>(W3o, W3OT, 512, CH);
    pack_plain<<<(3 * CH + 255) / 256, 256, 0, stream>>>(angwA, WANGA, 3, CH);

    ftrans_kernel<<<(BN * CH * NP + 255) / 256, 256, 0, stream>>>(features, F);
    knn_kernel<<<BN * NP / 4, 256, 0, stream>>>(coords, IDX);
    cosangle_kernel<<<(BN * NP * KNB + 255) / 256, 256, 0, stream>>>(coords, IDX, COSA);

    auto sfin = [&](int S, int Cc, int slot, int nch) {
        stats_final<<<BN * Cc, 256, 0, stream>>>(PART, STATS, S, Cc, slot, nch);
    };
    auto norm = [&](float* X, int S, int Cc, int slot, int act) {
        int tot = BN * S * Cc;
        norm_act<<<(tot + 255) / 256, 256, 0, stream>>>(X, STATS, S, Cc, slot, act);
    };

    // --- x1 block ---
    convA_kernel<<<BN * (NP / CA_PTS), 256, 0, stream>>>(F, IDX, WA1T, YA, PART);
    sfin(3 * NP, CH, 0, NP / CA_PTS * 2);
    pixel_gemm<<<BN * (NP / 8), 128, 8 * 384 * 4, stream>>>(YA, WB1T, X1, 384, CH, STATS, 0, PART);
    sfin(NP, CH, 1, NP / 8);
    norm(X1, NP, CH, 1, 0);

    // --- angle block ---
    angA_kernel<<<BN * (NP / 32), 128, 0, stream>>>(COSA, WANGA, YA, PART);
    sfin(3 * NP, CH, 2, NP / 32);
    pixel_gemm<<<BN * (NP / 8), 128, 8 * 384 * 4, stream>>>(YA, WBAT, FANG, 384, CH, STATS, 2, PART);
    sfin(NP, CH, 3, NP / 8);
    norm(FANG, NP, CH, 3, 0);

    // --- x2 block ---
    convA_kernel<<<BN * (NP / CA_PTS), 256, 0, stream>>>(X1, IDX, WA2T, YA, PART);
    sfin(3 * NP, CH, 4, NP / CA_PTS * 2);
    pixel_gemm<<<BN * (NP / 8), 128, 8 * 384 * 4, stream>>>(YA, WB2T, X2, 384, CH, STATS, 4, PART);
    sfin(NP, CH, 5, NP / 8);
    norm(X2, NP, CH, 5, 0);

    // --- head3 ---
    head3_kernel<<<BN * (NP / 8), 128, 0, stream>>>(F, X1, X2, FANG, W3T, Y3, PART);
    sfin(NP, CH, 8, NP / 8);

    // --- x1o path ---
    pixel_gemm<<<BN * (NP / 8), 128, 8 * 128 * 4, stream>>>(F, W1N, V1, 128, CH, STATS, -1, nullptr);
    gathermax_fused<<<BN * (NP / GM_PTS), CH, 0, stream>>>(F, W1U, V1, IDX, M1, PART, CH);
    sfin(NP * KNB, CH, 6, NP / GM_PTS);
    norm(M1, NP, CH, 6, 1);

    // --- x2o path ---
    pixel_gemm<<<BN * (NP / 8), 256, 8 * 128 * 4, stream>>>(M1, W2N, V2, 128, 256, STATS, -1, nullptr);
    gathermax_fused<<<BN * (NP / GM_PTS), 256, 0, stream>>>(M1, W2U, V2, IDX, M2, PART, 256);
    sfin(NP * KNB, 256, 7, NP / GM_PTS);
    norm(M2, NP, 256, 7, 1);

    // --- head3o + final ---
    head3o_kernel<<<BN * (NP / 8), 128, 0, stream>>>(F, M1, M2, W3OT, Y3O, PART);
    sfin(NP, CH, 9, NP / 8);
    final_kernel<<<BN * (NP / 64), 128, 0, stream>>>(Y3, Y3O, STATS, out);
}